// Round 6
// baseline (251.010 us; speedup 1.0000x reference)
//
#include <hip/hip_runtime.h>
#include <hip/hip_bf16.h>

#define M_NODES 50000
#define K_DIM   512
#define N_DIM   128

typedef short s16x8 __attribute__((ext_vector_type(8)));
typedef float f32x4 __attribute__((ext_vector_type(4)));

static __device__ __forceinline__ ushort f2bf(float f) {
  uint u = __float_as_uint(f);
  u += 0x7fff + ((u >> 16) & 1);   // RNE
  return (ushort)(u >> 16);
}

static __device__ __forceinline__ uint cvtpk(float lo, float hi) {
  uint r;
  asm("v_cvt_pk_bf16_f32 %0, %1, %2" : "=v"(r) : "v"(lo), "v"(hi));
  return r;
}

// async global->LDS, 16B per lane. LDS dest wave-uniform base (HW adds lane*16).
static __device__ __forceinline__ void g2l16(const void* g, void* l) {
  __builtin_amdgcn_global_load_lds((const __attribute__((address_space(1))) void*)g,
                                   (__attribute__((address_space(3))) void*)l, 16, 0, 0);
}

// ---------------- prep: zero d_out + Wt[col][k] = bf16(W[k][col]) -----------
__global__ __launch_bounds__(256) void prep_zero(const float* __restrict__ W,
                                                 ushort* __restrict__ Wt,
                                                 float4* __restrict__ o4, int n4) {
  const int t = blockIdx.x * 256 + threadIdx.x;
  const int stride = gridDim.x * 256;
  for (int i = t; i < n4; i += stride) o4[i] = make_float4(0.f, 0.f, 0.f, 0.f);
  if (t < 16384) {
    int k  = t >> 5;
    int c0 = (t & 31) * 4;
    float4 v = *reinterpret_cast<const float4*>(&W[(size_t)k * N_DIM + c0]);
    Wt[(size_t)(c0 + 0) * K_DIM + k] = f2bf(v.x);
    Wt[(size_t)(c0 + 1) * K_DIM + k] = f2bf(v.y);
    Wt[(size_t)(c0 + 2) * K_DIM + k] = f2bf(v.z);
    Wt[(size_t)(c0 + 3) * K_DIM + k] = f2bf(v.w);
  }
}

// ---------------- GEMM: S = X @ W, global_load_lds 2-phase, BM=64 -----------
// 64x128 tile, BK=32, 256 thr = 4 waves (2x2). Wave: 32x64 = 2x4 16x16 frags.
// Grid 782 -> ~3 blocks/CU (12 waves/CU). LDS dbuf 32 KB.
// A LDS [64 rows][8 chunks of 4 fp32], chunk XOR-swizzled by row&7 (source
// pre-swizzled, LDS dest linear). B LDS [128 cols][32 k] bf16, linear.
#define GBK 32
#define NKS (K_DIM / GBK)   // 16

__global__ __launch_bounds__(256, 4) void gemm_mfma(const float* __restrict__ X,
                                                    const ushort* __restrict__ Wt,
                                                    float* __restrict__ S) {
  __shared__ float  Albs[2][64 * 32];    // 8 KB each
  __shared__ ushort Blbs[2][128 * 32];   // 8 KB each

  const int tid = threadIdx.x;
  const int w   = tid >> 6;
  const int l   = tid & 63;
  const int l15 = l & 15, lg = l >> 4;
  const int wr  = w >> 1, wc = w & 1;
  const int row0 = blockIdx.x * 64;

  // staging source pointers (per-lane, pre-swizzled for A)
  const float* aSrc[2];
#pragma unroll
  for (int i = 0; i < 2; ++i) {
    int q = i * 256 + w * 64 + l;        // chunk 0..511
    int r = q >> 3;
    int c = (q & 7) ^ (r & 7);           // inverse swizzle on source
    int rg = row0 + r; if (rg >= M_NODES) rg = M_NODES - 1;
    aSrc[i] = X + (size_t)rg * K_DIM + c * 4;
  }
  const ushort* bSrc[2];
#pragma unroll
  for (int i = 0; i < 2; ++i) {
    int q = i * 256 + w * 64 + l;        // chunk 0..511
    int col = q >> 2, j = q & 3;
    bSrc[i] = Wt + (size_t)col * K_DIM + j * 8;
  }

  f32x4 acc[2][4];
#pragma unroll
  for (int am = 0; am < 2; ++am)
#pragma unroll
    for (int bn = 0; bn < 4; ++bn) acc[am][bn] = (f32x4){0.f, 0.f, 0.f, 0.f};

#define STAGE(buf, kk) { \
  _Pragma("unroll") for (int i = 0; i < 2; ++i) \
    g2l16(aSrc[i] + (kk), (char*)&Albs[buf][0] + (size_t)(i * 256 + w * 64) * 16); \
  _Pragma("unroll") for (int i = 0; i < 2; ++i) \
    g2l16(bSrc[i] + (kk), (char*)&Blbs[buf][0] + (size_t)(i * 256 + w * 64) * 16); }

#define COMPUTE(buf) { \
  s16x8 af[2], bfr[4]; \
  _Pragma("unroll") for (int am = 0; am < 2; ++am) { \
    const int r = wr * 32 + am * 16 + l15; \
    const int s = r & 7; \
    float4 f0 = *reinterpret_cast<const float4*>(&Albs[buf][(r * 8 + ((lg * 2) ^ s)) * 4]); \
    float4 f1 = *reinterpret_cast<const float4*>(&Albs[buf][(r * 8 + ((lg * 2 + 1) ^ s)) * 4]); \
    union { s16x8 v; uint u[4]; } a; \
    a.u[0] = cvtpk(f0.x, f0.y); a.u[1] = cvtpk(f0.z, f0.w); \
    a.u[2] = cvtpk(f1.x, f1.y); a.u[3] = cvtpk(f1.z, f1.w); \
    af[am] = a.v; } \
  _Pragma("unroll") for (int bn = 0; bn < 4; ++bn) { \
    const int c = wc * 64 + bn * 16 + l15; \
    bfr[bn] = *reinterpret_cast<const s16x8*>(&Blbs[buf][c * 32 + lg * 8]); } \
  _Pragma("unroll") for (int am = 0; am < 2; ++am) \
    _Pragma("unroll") for (int bn = 0; bn < 4; ++bn) \
      acc[am][bn] = __builtin_amdgcn_mfma_f32_16x16x32_bf16(af[am], bfr[bn], acc[am][bn], 0, 0, 0); }

  STAGE(0, 0)
  __syncthreads();
#pragma unroll
  for (int t = 0; t < NKS; ++t) {
    if (t + 1 < NKS) STAGE((t + 1) & 1, (t + 1) * GBK)
    COMPUTE(t & 1)
    __syncthreads();
  }
#undef STAGE
#undef COMPUTE

#pragma unroll
  for (int am = 0; am < 2; ++am) {
#pragma unroll
    for (int rr = 0; rr < 4; ++rr) {
      const int row = row0 + wr * 32 + am * 16 + lg * 4 + rr;
      if (row < M_NODES) {
        float* sp = S + (size_t)row * N_DIM + wc * 64 + l15;
#pragma unroll
        for (int bn = 0; bn < 4; ++bn)
          sp[bn * 16] = acc[am][bn][rr];
      }
    }
  }
}

// ---------------- SpMM: out = segment_sum(S[src]*val, dst), dst sorted ------
// Block 128 thr = 4 half-waves; each half-wave = 64 contiguous edges, lane owns
// a 4-col quad (float4 gathers, 512 B/row coalesced). Batch-8 double-buffer.
// Interior runs plain-store; first/last run of each chunk atomicAdd.
#define EPB 256
#define CHUNK 64
#define SB 8

__global__ __launch_bounds__(128, 4) void spmm_edges(const float* __restrict__ S,
                                                     const int* __restrict__ esrc,
                                                     const int* __restrict__ edst,
                                                     const float* __restrict__ eval,
                                                     float* __restrict__ out) {
  __shared__ int   s_src[EPB];
  __shared__ int   s_dst[EPB];
  __shared__ float s_val[EPB];

  const int e0  = blockIdx.x * EPB;
  const int tid = threadIdx.x;

#pragma unroll
  for (int i = 0; i < EPB / 128; ++i) {
    int idx = tid + i * 128;
    s_src[idx] = esrc[e0 + idx];
    s_dst[idx] = edst[e0 + idx];
    s_val[idx] = eval[e0 + idx];
  }
  __syncthreads();

  const int wid  = tid >> 6;
  const int l    = tid & 63;
  const int half = (wid << 1) | (l >> 5);   // 0..3
  const int hl   = l & 31;
  const int base = half * CHUNK;
  const int c0   = hl * 4;

  const int first = s_dst[base];
  int   cur = first;
  f32x4 acc = {0.f, 0.f, 0.f, 0.f};

  f32x4 bufA[SB], bufB[SB];

#define SLOAD(BUF, B) { \
  _Pragma("unroll") for (int j = 0; j < SB; ++j) \
    BUF[j] = *reinterpret_cast<const f32x4*>( \
        S + (size_t)s_src[base + (B) * SB + j] * N_DIM + c0); \
  __builtin_amdgcn_sched_barrier(0); }

#define FLUSH() { \
  float* op = out + (size_t)cur * N_DIM + c0; \
  if (cur == first) { \
    atomicAdd(op + 0, acc[0]); atomicAdd(op + 1, acc[1]); \
    atomicAdd(op + 2, acc[2]); atomicAdd(op + 3, acc[3]); \
  } else { \
    *reinterpret_cast<f32x4*>(op) = acc; \
  } \
  acc = (f32x4){0.f, 0.f, 0.f, 0.f}; }

#define SPROC(BUF, B) { \
  _Pragma("unroll") for (int j = 0; j < SB; ++j) { \
    const int e = base + (B) * SB + j; \
    const int d = s_dst[e]; \
    if (d != cur) { FLUSH() cur = d; } \
    const float vv = s_val[e]; \
    acc[0] += vv * BUF[j][0]; acc[1] += vv * BUF[j][1]; \
    acc[2] += vv * BUF[j][2]; acc[3] += vv * BUF[j][3]; } }

  SLOAD(bufA, 0)
#pragma unroll
  for (int b = 0; b < CHUNK / SB; b += 2) {
    if (b + 1 < CHUNK / SB) SLOAD(bufB, b + 1)
    SPROC(bufA, b)
    if (b + 2 < CHUNK / SB) SLOAD(bufA, b + 2)
    SPROC(bufB, b + 1)
  }
  {  // final run may span chunks/blocks -> atomic
    float* op = out + (size_t)cur * N_DIM + c0;
    atomicAdd(op + 0, acc[0]); atomicAdd(op + 1, acc[1]);
    atomicAdd(op + 2, acc[2]); atomicAdd(op + 3, acc[3]);
  }
#undef SLOAD
#undef SPROC
#undef FLUSH
}

// ---------------- launch ----------------
extern "C" void kernel_launch(void* const* d_in, const int* in_sizes, int n_in,
                              void* d_out, int out_size, void* d_ws, size_t ws_size,
                              hipStream_t stream) {
  const float* x        = (const float*)d_in[0];
  const int*   edge_src = (const int*)d_in[1];
  const int*   edge_dst = (const int*)d_in[2];
  const float* edge_val = (const float*)d_in[3];
  const float* weight   = (const float*)d_in[4];
  float*       out      = (float*)d_out;

  float*  support = (float*)d_ws;                                        // 25.6 MB
  ushort* wt      = (ushort*)((char*)d_ws + (size_t)M_NODES * N_DIM * 4);// 128 KB

  const int n_edges = in_sizes[1];

  prep_zero<<<dim3(512), dim3(256), 0, stream>>>(weight, wt, (float4*)d_out,
                                                 out_size / 4);

  gemm_mfma<<<dim3((M_NODES + 63) / 64), dim3(256), 0, stream>>>(x, wt, support);

  spmm_edges<<<dim3(n_edges / EPB), dim3(128), 0, stream>>>(support, edge_src,
                                                            edge_dst, edge_val, out);
}

// Round 7
// 214.129 us; speedup vs baseline: 1.1722x; 1.1722x over previous
//
#include <hip/hip_runtime.h>
#include <hip/hip_bf16.h>

#define M_NODES 50000
#define K_DIM   512
#define N_DIM   128

typedef short s16x8 __attribute__((ext_vector_type(8)));
typedef float f32x4 __attribute__((ext_vector_type(4)));

static __device__ __forceinline__ ushort f2bf(float f) {
  uint u = __float_as_uint(f);
  u += 0x7fff + ((u >> 16) & 1);   // RNE
  return (ushort)(u >> 16);
}

static __device__ __forceinline__ uint cvtpk(float lo, float hi) {
  uint r;
  asm("v_cvt_pk_bf16_f32 %0, %1, %2" : "=v"(r) : "v"(lo), "v"(hi));
  return r;
}

// async global->LDS, 16B per lane. LDS dest wave-uniform base (HW adds lane*16).
static __device__ __forceinline__ void g2l16(const void* g, void* l) {
  __builtin_amdgcn_global_load_lds((const __attribute__((address_space(1))) void*)g,
                                   (__attribute__((address_space(3))) void*)l, 16, 0, 0);
}

// ---------------- prep: zero d_out + Wt[col][k] = bf16(W[k][col]) -----------
__global__ __launch_bounds__(256) void prep_zero(const float* __restrict__ W,
                                                 ushort* __restrict__ Wt,
                                                 float4* __restrict__ o4, int n4) {
  const int t = blockIdx.x * 256 + threadIdx.x;
  const int stride = gridDim.x * 256;
  for (int i = t; i < n4; i += stride) o4[i] = make_float4(0.f, 0.f, 0.f, 0.f);
  if (t < 16384) {
    int k  = t >> 5;
    int c0 = (t & 31) * 4;
    float4 v = *reinterpret_cast<const float4*>(&W[(size_t)k * N_DIM + c0]);
    Wt[(size_t)(c0 + 0) * K_DIM + k] = f2bf(v.x);
    Wt[(size_t)(c0 + 1) * K_DIM + k] = f2bf(v.y);
    Wt[(size_t)(c0 + 2) * K_DIM + k] = f2bf(v.z);
    Wt[(size_t)(c0 + 3) * K_DIM + k] = f2bf(v.w);
  }
}

// ---------------- GEMM: Sb(bf16) = X @ W, global_load_lds 2-phase, BM=64 ----
// 64x128 tile, BK=32, 256 thr = 4 waves (2x2). Wave: 32x64 = 2x4 16x16 frags.
// A LDS [64 rows][8 chunks of 4 fp32], chunk XOR-swizzled by row&7 (source
// pre-swizzled, LDS dest linear). B LDS [128 cols][32 k] bf16, linear.
// Epilogue stores bf16 (support consumed only by spmm gather).
#define GBK 32
#define NKS (K_DIM / GBK)   // 16

__global__ __launch_bounds__(256, 4) void gemm_mfma(const float* __restrict__ X,
                                                    const ushort* __restrict__ Wt,
                                                    ushort* __restrict__ Sb) {
  __shared__ float  Albs[2][64 * 32];    // 8 KB each
  __shared__ ushort Blbs[2][128 * 32];   // 8 KB each

  const int tid = threadIdx.x;
  const int w   = tid >> 6;
  const int l   = tid & 63;
  const int l15 = l & 15, lg = l >> 4;
  const int wr  = w >> 1, wc = w & 1;
  const int row0 = blockIdx.x * 64;

  const float* aSrc[2];
#pragma unroll
  for (int i = 0; i < 2; ++i) {
    int q = i * 256 + w * 64 + l;        // chunk 0..511
    int r = q >> 3;
    int c = (q & 7) ^ (r & 7);           // inverse swizzle on source
    int rg = row0 + r; if (rg >= M_NODES) rg = M_NODES - 1;
    aSrc[i] = X + (size_t)rg * K_DIM + c * 4;
  }
  const ushort* bSrc[2];
#pragma unroll
  for (int i = 0; i < 2; ++i) {
    int q = i * 256 + w * 64 + l;        // chunk 0..511
    int col = q >> 2, j = q & 3;
    bSrc[i] = Wt + (size_t)col * K_DIM + j * 8;
  }

  f32x4 acc[2][4];
#pragma unroll
  for (int am = 0; am < 2; ++am)
#pragma unroll
    for (int bn = 0; bn < 4; ++bn) acc[am][bn] = (f32x4){0.f, 0.f, 0.f, 0.f};

#define STAGE(buf, kk) { \
  _Pragma("unroll") for (int i = 0; i < 2; ++i) \
    g2l16(aSrc[i] + (kk), (char*)&Albs[buf][0] + (size_t)(i * 256 + w * 64) * 16); \
  _Pragma("unroll") for (int i = 0; i < 2; ++i) \
    g2l16(bSrc[i] + (kk), (char*)&Blbs[buf][0] + (size_t)(i * 256 + w * 64) * 16); }

#define COMPUTE(buf) { \
  s16x8 af[2], bfr[4]; \
  _Pragma("unroll") for (int am = 0; am < 2; ++am) { \
    const int r = wr * 32 + am * 16 + l15; \
    const int s = r & 7; \
    float4 f0 = *reinterpret_cast<const float4*>(&Albs[buf][(r * 8 + ((lg * 2) ^ s)) * 4]); \
    float4 f1 = *reinterpret_cast<const float4*>(&Albs[buf][(r * 8 + ((lg * 2 + 1) ^ s)) * 4]); \
    union { s16x8 v; uint u[4]; } a; \
    a.u[0] = cvtpk(f0.x, f0.y); a.u[1] = cvtpk(f0.z, f0.w); \
    a.u[2] = cvtpk(f1.x, f1.y); a.u[3] = cvtpk(f1.z, f1.w); \
    af[am] = a.v; } \
  _Pragma("unroll") for (int bn = 0; bn < 4; ++bn) { \
    const int c = wc * 64 + bn * 16 + l15; \
    bfr[bn] = *reinterpret_cast<const s16x8*>(&Blbs[buf][c * 32 + lg * 8]); } \
  _Pragma("unroll") for (int am = 0; am < 2; ++am) \
    _Pragma("unroll") for (int bn = 0; bn < 4; ++bn) \
      acc[am][bn] = __builtin_amdgcn_mfma_f32_16x16x32_bf16(af[am], bfr[bn], acc[am][bn], 0, 0, 0); }

  STAGE(0, 0)
  __syncthreads();
#pragma unroll
  for (int t = 0; t < NKS; ++t) {
    if (t + 1 < NKS) STAGE((t + 1) & 1, (t + 1) * GBK)
    COMPUTE(t & 1)
    __syncthreads();
  }
#undef STAGE
#undef COMPUTE

#pragma unroll
  for (int am = 0; am < 2; ++am) {
#pragma unroll
    for (int rr = 0; rr < 4; ++rr) {
      const int row = row0 + wr * 32 + am * 16 + lg * 4 + rr;
      if (row < M_NODES) {
        ushort* sp = Sb + (size_t)row * N_DIM + wc * 64 + l15;
#pragma unroll
        for (int bn = 0; bn < 4; ++bn)
          sp[bn * 16] = f2bf(acc[am][bn][rr]);
      }
    }
  }
}

// ---------------- SpMM: out = segment_sum(Sb[src]*val, dst), dst sorted -----
// Block 128 thr = 2 waves; EACH WAVE owns its own 128-edge chunk: lane l =
// cols {2l, 2l+1}, one uint (2x bf16) load per edge -> wave reads the full
// 256 B row in ONE instruction. All flush branches wave-uniform (cur/first
// are wave scalars). 32-deep 2-stage pipeline. Interior runs plain float2
// store; first/last run of chunk atomicAdd.
#define EPB 256    // per block = 2 waves x 128
#define CPW 128    // edges per wave
#define SB 32

__global__ __launch_bounds__(128, 4) void spmm_edges(const ushort* __restrict__ Sb,
                                                     const int* __restrict__ esrc,
                                                     const int* __restrict__ edst,
                                                     const float* __restrict__ eval,
                                                     float* __restrict__ out) {
  __shared__ int   s_src[EPB];
  __shared__ int   s_dst[EPB];
  __shared__ float s_val[EPB];

  const int e0  = blockIdx.x * EPB;
  const int tid = threadIdx.x;

#pragma unroll
  for (int i = 0; i < EPB / 128; ++i) {
    int idx = tid + i * 128;
    s_src[idx] = esrc[e0 + idx];
    s_dst[idx] = edst[e0 + idx];
    s_val[idx] = eval[e0 + idx];
  }
  __syncthreads();

  const int w    = tid >> 6;
  const int l    = tid & 63;
  const int base = w * CPW;
  const uint colb = (uint)l * 4u;     // byte offset of col pair within 256 B row

  const int first = s_dst[base];
  int   cur = first;
  float ax = 0.f, ay = 0.f;

  uint bufA[SB], bufB[SB];

#define SLOAD(BUF, B) { \
  _Pragma("unroll") for (int j = 0; j < SB; ++j) \
    BUF[j] = *reinterpret_cast<const uint*>( \
        (const char*)Sb + (size_t)s_src[base + (B) * SB + j] * 256 + colb); }

#define FLUSH() { \
  float* op = out + (size_t)cur * N_DIM + l * 2; \
  if (cur == first) { atomicAdd(op, ax); atomicAdd(op + 1, ay); } \
  else { *reinterpret_cast<float2*>(op) = make_float2(ax, ay); } \
  ax = 0.f; ay = 0.f; }

#define SPROC(BUF, B) { \
  _Pragma("unroll") for (int j = 0; j < SB; ++j) { \
    const int e = base + (B) * SB + j; \
    const int d = s_dst[e]; \
    if (d != cur) { FLUSH() cur = d; } \
    const float vv = s_val[e]; \
    const float lo = __uint_as_float(BUF[j] << 16); \
    const float hi = __uint_as_float(BUF[j] & 0xffff0000u); \
    ax += vv * lo; ay += vv * hi; } }

  SLOAD(bufA, 0)
#pragma unroll
  for (int b = 0; b < CPW / SB; b += 2) {
    if (b + 1 < CPW / SB) SLOAD(bufB, b + 1)
    SPROC(bufA, b)
    if (b + 2 < CPW / SB) SLOAD(bufA, b + 2)
    SPROC(bufB, b + 1)
  }
  {  // final run may span chunks/blocks -> atomic
    float* op = out + (size_t)cur * N_DIM + l * 2;
    atomicAdd(op, ax); atomicAdd(op + 1, ay);
  }
#undef SLOAD
#undef SPROC
#undef FLUSH
}

// ---------------- launch ----------------
extern "C" void kernel_launch(void* const* d_in, const int* in_sizes, int n_in,
                              void* d_out, int out_size, void* d_ws, size_t ws_size,
                              hipStream_t stream) {
  const float* x        = (const float*)d_in[0];
  const int*   edge_src = (const int*)d_in[1];
  const int*   edge_dst = (const int*)d_in[2];
  const float* edge_val = (const float*)d_in[3];
  const float* weight   = (const float*)d_in[4];
  float*       out      = (float*)d_out;

  ushort* sb = (ushort*)d_ws;                                            // 12.8 MB
  ushort* wt = (ushort*)((char*)d_ws + (size_t)M_NODES * N_DIM * 2);     // 128 KB

  const int n_edges = in_sizes[1];

  prep_zero<<<dim3(512), dim3(256), 0, stream>>>(weight, wt, (float4*)d_out,
                                                 out_size / 4);

  gemm_mfma<<<dim3((M_NODES + 63) / 64), dim3(256), 0, stream>>>(x, wt, sb);

  spmm_edges<<<dim3(n_edges / EPB), dim3(128), 0, stream>>>(sb, edge_src,
                                                            edge_dst, edge_val, out);
}

// Round 8
// 213.154 us; speedup vs baseline: 1.1776x; 1.0046x over previous
//
#include <hip/hip_runtime.h>
#include <hip/hip_bf16.h>

#define M_NODES 50000
#define K_DIM   512
#define N_DIM   128

typedef short s16x8 __attribute__((ext_vector_type(8)));
typedef float f32x4 __attribute__((ext_vector_type(4)));

static __device__ __forceinline__ ushort f2bf(float f) {
  uint u = __float_as_uint(f);
  u += 0x7fff + ((u >> 16) & 1);   // RNE
  return (ushort)(u >> 16);
}

static __device__ __forceinline__ uint cvtpk(float lo, float hi) {
  uint r;
  asm("v_cvt_pk_bf16_f32 %0, %1, %2" : "=v"(r) : "v"(lo), "v"(hi));
  return r;
}

// async global->LDS, 16B per lane. Global src per-lane OK; LDS dest must be
// wave-uniform base (HW adds lane*16).
static __device__ __forceinline__ void g2l16(const void* g, void* l) {
  __builtin_amdgcn_global_load_lds((const __attribute__((address_space(1))) void*)g,
                                   (__attribute__((address_space(3))) void*)l, 16, 0, 0);
}

// ---------------- prep: zero d_out + Wt[col][k] = bf16(W[k][col]) -----------
__global__ __launch_bounds__(256) void prep_zero(const float* __restrict__ W,
                                                 ushort* __restrict__ Wt,
                                                 float4* __restrict__ o4, int n4) {
  const int t = blockIdx.x * 256 + threadIdx.x;
  const int stride = gridDim.x * 256;
  for (int i = t; i < n4; i += stride) o4[i] = make_float4(0.f, 0.f, 0.f, 0.f);
  if (t < 16384) {
    int k  = t >> 5;
    int c0 = (t & 31) * 4;
    float4 v = *reinterpret_cast<const float4*>(&W[(size_t)k * N_DIM + c0]);
    Wt[(size_t)(c0 + 0) * K_DIM + k] = f2bf(v.x);
    Wt[(size_t)(c0 + 1) * K_DIM + k] = f2bf(v.y);
    Wt[(size_t)(c0 + 2) * K_DIM + k] = f2bf(v.z);
    Wt[(size_t)(c0 + 3) * K_DIM + k] = f2bf(v.w);
  }
}

// ---------------- GEMM: Sb(bf16) = X @ W, global_load_lds 2-phase, BM=64 ----
#define GBK 32
#define NKS (K_DIM / GBK)   // 16

__global__ __launch_bounds__(256, 4) void gemm_mfma(const float* __restrict__ X,
                                                    const ushort* __restrict__ Wt,
                                                    ushort* __restrict__ Sb) {
  __shared__ float  Albs[2][64 * 32];    // 8 KB each
  __shared__ ushort Blbs[2][128 * 32];   // 8 KB each

  const int tid = threadIdx.x;
  const int w   = tid >> 6;
  const int l   = tid & 63;
  const int l15 = l & 15, lg = l >> 4;
  const int wr  = w >> 1, wc = w & 1;
  const int row0 = blockIdx.x * 64;

  const float* aSrc[2];
#pragma unroll
  for (int i = 0; i < 2; ++i) {
    int q = i * 256 + w * 64 + l;        // chunk 0..511
    int r = q >> 3;
    int c = (q & 7) ^ (r & 7);           // inverse swizzle on source
    int rg = row0 + r; if (rg >= M_NODES) rg = M_NODES - 1;
    aSrc[i] = X + (size_t)rg * K_DIM + c * 4;
  }
  const ushort* bSrc[2];
#pragma unroll
  for (int i = 0; i < 2; ++i) {
    int q = i * 256 + w * 64 + l;        // chunk 0..511
    int col = q >> 2, j = q & 3;
    bSrc[i] = Wt + (size_t)col * K_DIM + j * 8;
  }

  f32x4 acc[2][4];
#pragma unroll
  for (int am = 0; am < 2; ++am)
#pragma unroll
    for (int bn = 0; bn < 4; ++bn) acc[am][bn] = (f32x4){0.f, 0.f, 0.f, 0.f};

#define STAGE(buf, kk) { \
  _Pragma("unroll") for (int i = 0; i < 2; ++i) \
    g2l16(aSrc[i] + (kk), (char*)&Albs[buf][0] + (size_t)(i * 256 + w * 64) * 16); \
  _Pragma("unroll") for (int i = 0; i < 2; ++i) \
    g2l16(bSrc[i] + (kk), (char*)&Blbs[buf][0] + (size_t)(i * 256 + w * 64) * 16); }

#define COMPUTE(buf) { \
  s16x8 af[2], bfr[4]; \
  _Pragma("unroll") for (int am = 0; am < 2; ++am) { \
    const int r = wr * 32 + am * 16 + l15; \
    const int s = r & 7; \
    float4 f0 = *reinterpret_cast<const float4*>(&Albs[buf][(r * 8 + ((lg * 2) ^ s)) * 4]); \
    float4 f1 = *reinterpret_cast<const float4*>(&Albs[buf][(r * 8 + ((lg * 2 + 1) ^ s)) * 4]); \
    union { s16x8 v; uint u[4]; } a; \
    a.u[0] = cvtpk(f0.x, f0.y); a.u[1] = cvtpk(f0.z, f0.w); \
    a.u[2] = cvtpk(f1.x, f1.y); a.u[3] = cvtpk(f1.z, f1.w); \
    af[am] = a.v; } \
  _Pragma("unroll") for (int bn = 0; bn < 4; ++bn) { \
    const int c = wc * 64 + bn * 16 + l15; \
    bfr[bn] = *reinterpret_cast<const s16x8*>(&Blbs[buf][c * 32 + lg * 8]); } \
  _Pragma("unroll") for (int am = 0; am < 2; ++am) \
    _Pragma("unroll") for (int bn = 0; bn < 4; ++bn) \
      acc[am][bn] = __builtin_amdgcn_mfma_f32_16x16x32_bf16(af[am], bfr[bn], acc[am][bn], 0, 0, 0); }

  STAGE(0, 0)
  __syncthreads();
#pragma unroll
  for (int t = 0; t < NKS; ++t) {
    if (t + 1 < NKS) STAGE((t + 1) & 1, (t + 1) * GBK)
    COMPUTE(t & 1)
    __syncthreads();
  }
#undef STAGE
#undef COMPUTE

#pragma unroll
  for (int am = 0; am < 2; ++am) {
#pragma unroll
    for (int rr = 0; rr < 4; ++rr) {
      const int row = row0 + wr * 32 + am * 16 + lg * 4 + rr;
      if (row < M_NODES) {
        ushort* sp = Sb + (size_t)row * N_DIM + wc * 64 + l15;
#pragma unroll
        for (int bn = 0; bn < 4; ++bn)
          sp[bn * 16] = f2bf(acc[am][bn][rr]);
      }
    }
  }
}

// ---------------- SpMM: out = segment_sum(Sb[src]*val, dst), dst sorted -----
// Block 128 thr = 2 waves; each wave owns 128 contiguous edges. Gathered rows
// are DMA-staged into per-wave LDS via global_load_lds (per-lane gather src,
// cannot be sunk by the compiler), 2-deep buffer, counted s_waitcnt vmcnt.
// Batch = 16 edges = 4 g2l16 (each instr: 4 rows x 256 B, 16 lanes/row).
// Processing: lane l owns cols {2l,2l+1}, one uint LDS read per edge
// (2 lanes/bank = conflict-free). Run flush branches wave-uniform.
#define EPB 256    // per block = 2 waves x 128
#define CPW 128    // edges per wave
#define EB  16     // edges per stage batch
#define NBATCH (CPW / EB)   // 8

__global__ __launch_bounds__(128, 4) void spmm_edges(const ushort* __restrict__ Sb,
                                                     const int* __restrict__ esrc,
                                                     const int* __restrict__ edst,
                                                     const float* __restrict__ eval,
                                                     float* __restrict__ out) {
  __shared__ ushort rows[2][2][EB * 128];   // [wave][buf] 4 KB each, 16 KB total
  __shared__ int   s_src[EPB];
  __shared__ int   s_dst[EPB];
  __shared__ float s_val[EPB];

  const int e0  = blockIdx.x * EPB;
  const int tid = threadIdx.x;

#pragma unroll
  for (int i = 0; i < EPB / 128; ++i) {
    int idx = tid + i * 128;
    s_src[idx] = esrc[e0 + idx];
    s_dst[idx] = edst[e0 + idx];
    s_val[idx] = eval[e0 + idx];
  }
  __syncthreads();

  const int w    = tid >> 6;
  const int l    = tid & 63;
  const int base = w * CPW;

  const int first = s_dst[base];
  int   cur = first;
  float ax = 0.f, ay = 0.f;

  // stage batch b of this wave's chunk into rows[w][buf]
#define SSTAGE(buf, b) { \
  _Pragma("unroll") for (int i = 0; i < EB / 4; ++i) { \
    const int er = base + (b) * EB + i * 4 + (l >> 4); \
    const char* src = (const char*)Sb + (size_t)s_src[er] * 256 + (l & 15) * 16; \
    g2l16(src, (char*)&rows[w][buf][0] + i * 1024); } }

#define FLUSH() { \
  float* op = out + (size_t)cur * N_DIM + l * 2; \
  if (cur == first) { atomicAdd(op, ax); atomicAdd(op + 1, ay); } \
  else { *reinterpret_cast<float2*>(op) = make_float2(ax, ay); } \
  ax = 0.f; ay = 0.f; }

#define SPROCB(buf, b) { \
  _Pragma("unroll") for (int j = 0; j < EB; ++j) { \
    const int e = base + (b) * EB + j; \
    const int d = s_dst[e]; \
    if (d != cur) { FLUSH() cur = d; } \
    const float vv = s_val[e]; \
    const uint pv = *reinterpret_cast<const uint*>(&rows[w][buf][j * 128 + l * 2]); \
    ax += vv * __uint_as_float(pv << 16); \
    ay += vv * __uint_as_float(pv & 0xffff0000u); } }

  SSTAGE(0, 0)
#pragma unroll
  for (int b = 0; b < NBATCH; ++b) {
    if (b + 1 < NBATCH) {
      SSTAGE((b + 1) & 1, b + 1)
      asm volatile("s_waitcnt vmcnt(4)" ::: "memory");   // current batch landed
    } else {
      asm volatile("s_waitcnt vmcnt(0)" ::: "memory");
    }
    __builtin_amdgcn_sched_barrier(0);
    SPROCB(b & 1, b)
  }
  {  // final run may span chunks/blocks -> atomic
    float* op = out + (size_t)cur * N_DIM + l * 2;
    atomicAdd(op, ax); atomicAdd(op + 1, ay);
  }
#undef SSTAGE
#undef SPROCB
#undef FLUSH
}

// ---------------- launch ----------------
extern "C" void kernel_launch(void* const* d_in, const int* in_sizes, int n_in,
                              void* d_out, int out_size, void* d_ws, size_t ws_size,
                              hipStream_t stream) {
  const float* x        = (const float*)d_in[0];
  const int*   edge_src = (const int*)d_in[1];
  const int*   edge_dst = (const int*)d_in[2];
  const float* edge_val = (const float*)d_in[3];
  const float* weight   = (const float*)d_in[4];
  float*       out      = (float*)d_out;

  ushort* sb = (ushort*)d_ws;                                            // 12.8 MB
  ushort* wt = (ushort*)((char*)d_ws + (size_t)M_NODES * N_DIM * 2);     // 128 KB

  const int n_edges = in_sizes[1];

  prep_zero<<<dim3(512), dim3(256), 0, stream>>>(weight, wt, (float4*)d_out,
                                                 out_size / 4);

  gemm_mfma<<<dim3((M_NODES + 63) / 64), dim3(256), 0, stream>>>(x, wt, sb);

  spmm_edges<<<dim3(n_edges / EPB), dim3(128), 0, stream>>>(sb, edge_src,
                                                            edge_dst, edge_val, out);
}